// Round 6
// baseline (84.677 us; speedup 1.0000x reference)
//
#include <hip/hip_runtime.h>
#include <hip/hip_bf16.h>

typedef __attribute__((ext_vector_type(8))) short short8;
typedef __attribute__((ext_vector_type(4))) float f32x4;
typedef __attribute__((ext_vector_type(16))) float f32x16;

#define DEVI __device__ __forceinline__

DEVI unsigned short f2bf(float f) {
  union { float f; unsigned int u; } v; v.f = f;
  unsigned int r = v.u + 0x7fffu + ((v.u >> 16) & 1u);
  return (unsigned short)(r >> 16);
}

// direct global->LDS, 16B per lane. dest = wave-uniform base + lane*16 (linear).
#define GLDS16(gp, lp)                                                         \
  __builtin_amdgcn_global_load_lds(                                            \
      (const __attribute__((address_space(1))) unsigned int*)(uintptr_t)(gp),  \
      (__attribute__((address_space(3))) unsigned int*)(uintptr_t)(lp), 16, 0, 0)

// problem sizes
#define SB 4
#define SS 2048
#define SD 256
#define SH 8
#define SDH 32
#define SM 8192  // B*S

// softmax scale folded into Q:  (1/sqrt(S)) * log2(e)
#define QSCALE 0.0318793654f

// workspace layout (ushort element offsets)
#define XBF_OFF 0
#define W_OFF   (SM * SD)                 // 4 weights bf16, contiguous: Wq,Wk,Wv,Wf
#define Q_OFF   (W_OFF + 4 * SD * SD)     // [BH][S][dh]   (Q pre-scaled by QSCALE)
#define K_OFF   (Q_OFF + SM * SD)         // [BH][S][dh]
#define VT_OFF  (K_OFF + SM * SD)         // [BH][dh][S]  (V transposed)
#define AO_OFF  (VT_OFF + SM * SD)        // [M][D] attention output

// ---------------- kernel 0: fp32 -> bf16 conversion ----------------
__global__ __launch_bounds__(256) void convert_k(
    const float* __restrict__ X, const float* __restrict__ Wq,
    const float* __restrict__ Wk, const float* __restrict__ Wv,
    const float* __restrict__ Wf, unsigned short* __restrict__ ws) {
  const int XN = SM * SD;   // 2097152
  const int WN = SD * SD;   // 65536
  int i4 = (blockIdx.x * 256 + threadIdx.x) * 4;
  const float* src; unsigned short* dst; int idx;
  if (i4 < XN)             { src = X;  dst = ws + XBF_OFF;      idx = i4; }
  else if (i4 < XN + WN)   { src = Wq; dst = ws + W_OFF;        idx = i4 - XN; }
  else if (i4 < XN + 2*WN) { src = Wk; dst = ws + W_OFF + WN;   idx = i4 - XN - WN; }
  else if (i4 < XN + 3*WN) { src = Wv; dst = ws + W_OFF + 2*WN; idx = i4 - XN - 2*WN; }
  else if (i4 < XN + 4*WN) { src = Wf; dst = ws + W_OFF + 3*WN; idx = i4 - XN - 3*WN; }
  else return;
  float4 v = *reinterpret_cast<const float4*>(src + idx);
  unsigned short o[4] = { f2bf(v.x), f2bf(v.y), f2bf(v.z), f2bf(v.w) };
  *reinterpret_cast<uint2*>(dst + idx) = *reinterpret_cast<const uint2*>(o);
}

// ---------------- kernel 1: fused QKV projection, 128x128 tile ----------------
// N dim = 768 (Wq|Wk|Wv concatenated). z = n0>>8 uniform per block.
// Epilogue goes through LDS so every global store is coalesced.
__global__ __launch_bounds__(256) void qkv_k(const unsigned short* __restrict__ ws_c,
                                             unsigned short* __restrict__ ws) {
  __shared__ __align__(16) unsigned short Atile[128][72];
  __shared__ __align__(16) unsigned short Btile[128][72];
  const unsigned short* Xb = ws_c + XBF_OFF;
  const unsigned short* Wall = ws_c + W_OFF;  // [768][256] concat
  int tid = threadIdx.x, w = tid >> 6, lane = tid & 63, g = lane >> 4, r = lane & 15;
  int m0 = blockIdx.x * 128, n0 = blockIdx.y * 128;
  int wr = (w >> 1) * 64, wc = (w & 1) * 64;
  f32x4 acc[4][4] = {};
  int srow = tid >> 3, scol = (tid & 7) * 8;
  short8 a[4], b[4];
#pragma unroll
  for (int p = 0; p < 4; ++p) {
    a[p] = *reinterpret_cast<const short8*>(Xb + (m0 + srow + p * 32) * SD + scol);
    b[p] = *reinterpret_cast<const short8*>(Wall + (n0 + srow + p * 32) * SD + scol);
  }
  for (int k0 = 0; k0 < SD; k0 += 64) {
    __syncthreads();
#pragma unroll
    for (int p = 0; p < 4; ++p) {
      *reinterpret_cast<short8*>(&Atile[srow + p * 32][scol]) = a[p];
      *reinterpret_cast<short8*>(&Btile[srow + p * 32][scol]) = b[p];
    }
    __syncthreads();
    if (k0 + 64 < SD) {  // prefetch next K-slice under compute
#pragma unroll
      for (int p = 0; p < 4; ++p) {
        a[p] = *reinterpret_cast<const short8*>(Xb + (m0 + srow + p * 32) * SD + k0 + 64 + scol);
        b[p] = *reinterpret_cast<const short8*>(Wall + (n0 + srow + p * 32) * SD + k0 + 64 + scol);
      }
    }
#pragma unroll
    for (int ks = 0; ks < 2; ++ks) {
      short8 af[4], bf[4];
#pragma unroll
      for (int i = 0; i < 4; ++i)
        af[i] = *reinterpret_cast<const short8*>(&Atile[wr + i * 16 + r][ks * 32 + g * 8]);
#pragma unroll
      for (int j = 0; j < 4; ++j)
        bf[j] = *reinterpret_cast<const short8*>(&Btile[wc + j * 16 + r][ks * 32 + g * 8]);
#pragma unroll
      for (int i = 0; i < 4; ++i)
#pragma unroll
        for (int j = 0; j < 4; ++j)
          acc[i][j] = __builtin_amdgcn_mfma_f32_16x16x32_bf16(af[i], bf[j], acc[i][j], 0, 0, 0);
    }
  }
  int z = n0 >> 8;          // 0=Q 1=K 2=V
  int nbase = n0 & 255;
  int b_ = m0 >> 11, sbase = m0 & 2047;
  float qs = (z == 0) ? QSCALE : 1.0f;
  unsigned short* Vt = &Btile[0][0];  // reused as [64][136]
#pragma unroll
  for (int p = 0; p < 2; ++p) {       // n-half pass: cols p*64 .. p*64+63
    __syncthreads();
    if ((w & 1) == p) {
      if (z < 2) {
#pragma unroll
        for (int i = 0; i < 4; ++i)
#pragma unroll
          for (int j = 0; j < 4; ++j)
#pragma unroll
            for (int jj = 0; jj < 4; ++jj)
              Atile[wr + i * 16 + g * 4 + jj][j * 16 + r] = f2bf(acc[i][j][jj] * qs);
      } else {
#pragma unroll
        for (int i = 0; i < 4; ++i)
#pragma unroll
          for (int j = 0; j < 4; ++j) {
            unsigned short o4[4];
#pragma unroll
            for (int jj = 0; jj < 4; ++jj) o4[jj] = f2bf(acc[i][j][jj]);
            *reinterpret_cast<uint2*>(&Vt[(j * 16 + r) * 136 + wr + i * 16 + g * 4]) =
                *reinterpret_cast<const uint2*>(o4);
          }
      }
    }
    __syncthreads();
    if (z < 2) {
      unsigned short* out = ws + (z == 0 ? Q_OFF : K_OFF);
      int h0 = (nbase + p * 64) >> 5;
#pragma unroll
      for (int it = 0; it < 4; ++it) {
        int c = it * 256 + tid;                  // 1024 chunks of 16B
        int m = c >> 3, cr = c & 7, hl = cr >> 2, ch = cr & 3;
        short8 val = *reinterpret_cast<const short8*>(&Atile[m][hl * 32 + ch * 8]);
        int h = h0 + hl;
        *reinterpret_cast<short8*>(
            out + (((b_ << 3) + h) * SS + sbase + m) * SDH + ch * 8) = val;
      }
    } else {
      unsigned short* out = ws + VT_OFF;
      int nb = nbase + p * 64;
#pragma unroll
      for (int it = 0; it < 4; ++it) {
        int c = it * 256 + tid;                  // 1024 chunks of 16B
        int nl = c >> 4, ch = c & 15;
        short8 val = *reinterpret_cast<const short8*>(&Vt[nl * 136 + ch * 8]);
        int col = nb + nl, h = col >> 5, d = col & 31;
        *reinterpret_cast<short8*>(
            out + ((((b_ << 3) + h) << 5) + d) * SS + sbase + ch * 8) = val;
      }
    }
  }
}

// ---------------- kernel 2: flash attention (INSTRUMENTED: x2 idempotent) ----
// Body identical to R4; runs twice with O/L re-init and identical AO writes so
// the dispatch exceeds the 43us harness fills and surfaces in top-5 with
// counters. True attn time = dur_us/2 (also = Dtotal vs R4's 59.1).
__global__ __launch_bounds__(512, 4) void attn_k(const unsigned short* __restrict__ ws_c,
                                                 unsigned short* __restrict__ ws) {
  __shared__ __align__(16) unsigned short Kb[2][2][64 * 32];  // [grp][buf] linear
  __shared__ __align__(16) unsigned short Vb[2][2][32 * 64];
  int tid = threadIdx.x, w = tid >> 6, lane = tid & 63;
  int wg = w >> 2, wl = w & 3, gtid = tid & 255;
  int n32 = lane & 31, hi = lane >> 5;
  // XCD-aware swizzle (512 % 8 == 0 -> bijective): 4 heads per XCD
  int wgid = ((blockIdx.x & 7) << 6) + (blockIdx.x >> 3);
  int bh = wgid >> 4, qb = wgid & 15;
  int q0 = qb * 128 + wl * 32;
  const unsigned short* Qh = ws_c + Q_OFF + bh * (SS * SDH);
  const unsigned short* Kg = ws_c + K_OFF + (bh * SS + wg * 1024) * SDH;
  const unsigned short* Vg = ws_c + VT_OFF + bh * (SDH * SS) + wg * 1024;
  // Q B-frags: lane holds col q=n32, k = 8*hi + j (dh halves)
  short8 qB0 = *reinterpret_cast<const short8*>(Qh + (q0 + n32) * SDH + 8 * hi);
  short8 qB1 = *reinterpret_cast<const short8*>(Qh + (q0 + n32) * SDH + 16 + 8 * hi);
  // staging source addresses (inverse-swizzled): lane L -> LDS byte L*16
  int krow = gtid >> 2, kch = (gtid & 3) ^ (krow & 3);
  const unsigned short* gK = Kg + krow * SDH + kch * 8;
  int vrow = gtid >> 3, vch = (gtid & 7) ^ (vrow & 7);
  const unsigned short* gV = Vg + vrow * SS + vch * 8;
  int wv = gtid >> 6;  // wave index within group
  unsigned short* lK[2] = { &Kb[wg][0][wv * 512], &Kb[wg][1][wv * 512] };
  unsigned short* lV[2] = { &Vb[wg][0][wv * 512], &Vb[wg][1][wv * 512] };
  for (int rep = 0; rep < 2; ++rep) {
    if (rep) __syncthreads();  // protect aliased OC/LC scratch from new staging
    GLDS16(gK, lK[0]);
    GLDS16(gV, lV[0]);
    f32x16 O = {};
    float Lacc = 0.f;
    for (int t = 0; t < 16; ++t) {
      const unsigned short* Kbase = &Kb[wg][t & 1][0];
      const unsigned short* Vbase = &Vb[wg][t & 1][0];
      if (t < 15) {
        GLDS16(gK + (t + 1) * 64 * SDH, lK[(t + 1) & 1]);
        GLDS16(gV + (t + 1) * 64, lV[(t + 1) & 1]);
        asm volatile("s_waitcnt vmcnt(2)" ::: "memory");  // tile t landed
      } else {
        asm volatile("s_waitcnt vmcnt(0)" ::: "memory");
      }
      __builtin_amdgcn_s_barrier();
      // K frags, both 32-kv subtiles (swizzled chunk c' = cR ^ (row&3))
      short8 kA00 = *reinterpret_cast<const short8*>(Kbase + n32 * 32 + ((hi ^ (n32 & 3)) * 8));
      short8 kA01 = *reinterpret_cast<const short8*>(Kbase + n32 * 32 + (((2 + hi) ^ (n32 & 3)) * 8));
      short8 kA10 = *reinterpret_cast<const short8*>(Kbase + (32 + n32) * 32 + ((hi ^ (n32 & 3)) * 8));
      short8 kA11 = *reinterpret_cast<const short8*>(Kbase + (32 + n32) * 32 + (((2 + hi) ^ (n32 & 3)) * 8));
      f32x16 a0 = {}, a1 = {};
      __builtin_amdgcn_s_setprio(1);
      a0 = __builtin_amdgcn_mfma_f32_32x32x16_bf16(kA00, qB0, a0, 0, 0, 0);
      a1 = __builtin_amdgcn_mfma_f32_32x32x16_bf16(kA10, qB0, a1, 0, 0, 0);
      a0 = __builtin_amdgcn_mfma_f32_32x32x16_bf16(kA01, qB1, a0, 0, 0, 0);
      a1 = __builtin_amdgcn_mfma_f32_32x32x16_bf16(kA11, qB1, a1, 0, 0, 0);
      __builtin_amdgcn_s_setprio(0);
      // p = exp2(s); lane holds kv(reg,hi) = (reg&3) + 8*(reg>>2) + 4*hi
#pragma unroll
      for (int i = 0; i < 16; ++i) a0[i] = __builtin_amdgcn_exp2f(a0[i]);
#pragma unroll
      for (int i = 0; i < 16; ++i) a1[i] = __builtin_amdgcn_exp2f(a1[i]);
      float s0 = 0.f, s1 = 0.f;
#pragma unroll
      for (int i = 0; i < 8; ++i) { s0 += a0[2 * i] + a1[2 * i]; s1 += a0[2 * i + 1] + a1[2 * i + 1]; }
      Lacc += s0 + s1;
      // P -> PV A-frags via cvt_pk + permlane32_swap (pair order derived R1)
      unsigned int pk0[8], pk1[8];
#pragma unroll
      for (int i = 0; i < 8; ++i) {
        unsigned int r0, r1;
        asm("v_cvt_pk_bf16_f32 %0, %1, %2" : "=v"(r0) : "v"(a0[2 * i]), "v"(a0[2 * i + 1]));
        asm("v_cvt_pk_bf16_f32 %0, %1, %2" : "=v"(r1) : "v"(a1[2 * i]), "v"(a1[2 * i + 1]));
        pk0[i] = r0; pk1[i] = r1;
      }
      asm("v_permlane32_swap_b32 %0, %1" : "+v"(pk0[0]), "+v"(pk0[2]));
      asm("v_permlane32_swap_b32 %0, %1" : "+v"(pk0[1]), "+v"(pk0[3]));
      asm("v_permlane32_swap_b32 %0, %1" : "+v"(pk0[4]), "+v"(pk0[6]));
      asm("v_permlane32_swap_b32 %0, %1" : "+v"(pk0[5]), "+v"(pk0[7]));
      asm("v_permlane32_swap_b32 %0, %1" : "+v"(pk1[0]), "+v"(pk1[2]));
      asm("v_permlane32_swap_b32 %0, %1" : "+v"(pk1[1]), "+v"(pk1[3]));
      asm("v_permlane32_swap_b32 %0, %1" : "+v"(pk1[4]), "+v"(pk1[6]));
      asm("v_permlane32_swap_b32 %0, %1" : "+v"(pk1[5]), "+v"(pk1[7]));
      union { unsigned int u[4]; short8 sv; } A10, A20, A11, A21;
      A10.u[0] = pk0[0]; A10.u[1] = pk0[1]; A10.u[2] = pk0[2]; A10.u[3] = pk0[3];
      A20.u[0] = pk0[4]; A20.u[1] = pk0[5]; A20.u[2] = pk0[6]; A20.u[3] = pk0[7];
      A11.u[0] = pk1[0]; A11.u[1] = pk1[1]; A11.u[2] = pk1[2]; A11.u[3] = pk1[3];
      A21.u[0] = pk1[4]; A21.u[1] = pk1[5]; A21.u[2] = pk1[6]; A21.u[3] = pk1[7];
      // V frags (swizzled chunk c' = cV ^ (row&7)), loaded late to cut VGPR peak
      short8 vB00 = *reinterpret_cast<const short8*>(Vbase + n32 * 64 + ((hi ^ (n32 & 7)) * 8));
      short8 vB01 = *reinterpret_cast<const short8*>(Vbase + n32 * 64 + (((2 + hi) ^ (n32 & 7)) * 8));
      short8 vB10 = *reinterpret_cast<const short8*>(Vbase + n32 * 64 + (((4 + hi) ^ (n32 & 7)) * 8));
      short8 vB11 = *reinterpret_cast<const short8*>(Vbase + n32 * 64 + (((6 + hi) ^ (n32 & 7)) * 8));
      __builtin_amdgcn_s_setprio(1);
      O = __builtin_amdgcn_mfma_f32_32x32x16_bf16(A10.sv, vB00, O, 0, 0, 0);
      O = __builtin_amdgcn_mfma_f32_32x32x16_bf16(A20.sv, vB01, O, 0, 0, 0);
      O = __builtin_amdgcn_mfma_f32_32x32x16_bf16(A11.sv, vB10, O, 0, 0, 0);
      O = __builtin_amdgcn_mfma_f32_32x32x16_bf16(A21.sv, vB11, O, 0, 0, 0);
      __builtin_amdgcn_s_setprio(0);
      __builtin_amdgcn_s_barrier();
    }
    // combine the two kv-groups' partial (O, L); scratch aliased onto K/V tiles
    __syncthreads();
    float* OCp = reinterpret_cast<float*>(&Kb[0][0][0]);   // 4096 floats = 16KB
    float* LCp = reinterpret_cast<float*>(&Vb[0][0][0]);   // 256 + 128 floats
    if (wg == 1) {
#pragma unroll
      for (int i = 0; i < 16; ++i) OCp[(wl * 64 + lane) * 16 + i] = O[i];
      LCp[wl * 64 + lane] = Lacc;
    }
    __syncthreads();
    if (wg == 0) {
#pragma unroll
      for (int i = 0; i < 16; ++i) O[i] += OCp[(wl * 64 + lane) * 16 + i];
      Lacc += LCp[wl * 64 + lane];
      float Lt = Lacc + __shfl_xor(Lacc, 32);
      float* Linv = LCp + 256 + wl * 32;
      if (lane < 32) Linv[n32] = 1.0f / Lt;
      int b = bh >> 3, h = bh & 7;
      unsigned short* AO = ws + AO_OFF;
#pragma unroll
      for (int rr = 0; rr < 16; ++rr) {
        int q = (rr & 3) + 8 * (rr >> 2) + 4 * hi;
        AO[(b * SS + q0 + q) * SD + h * SDH + n32] = f2bf(O[rr] * Linv[q]);
      }
    }
  }
}

// ---------------- kernel 3: out-proj + bias + residual + LayerNorm ----------------
__global__ __launch_bounds__(256) void final_k(
    const unsigned short* __restrict__ ws_c, const float* __restrict__ X,
    const float* __restrict__ bfv, const float* __restrict__ gamma,
    const float* __restrict__ beta, float* __restrict__ out) {
  __shared__ __align__(16) unsigned short Al[32][72];
  __shared__ __align__(16) unsigned short Bl[256][72];
  __shared__ float Cl[32][257];
  const unsigned short* AO = ws_c + AO_OFF;
  const unsigned short* Wf = ws_c + W_OFF + 3 * (SD * SD);
  int tid = threadIdx.x, w = tid >> 6, lane = tid & 63, g = lane >> 4, r = lane & 15;
  int m0 = blockIdx.x * 32;
  f32x4 acc[2][4] = {};
  int arow = tid >> 3, acol = (tid & 7) * 8;
  for (int k0 = 0; k0 < SD; k0 += 64) {
    short8 av = *reinterpret_cast<const short8*>(AO + (m0 + arow) * SD + k0 + acol);
    short8 bv[8];
#pragma unroll
    for (int i = 0; i < 8; i++)
      bv[i] = *reinterpret_cast<const short8*>(Wf + (i * 32 + arow) * SD + k0 + acol);
    __syncthreads();
    *reinterpret_cast<short8*>(&Al[arow][acol]) = av;
#pragma unroll
    for (int i = 0; i < 8; i++)
      *reinterpret_cast<short8*>(&Bl[i * 32 + arow][acol]) = bv[i];
    __syncthreads();
#pragma unroll
    for (int ks = 0; ks < 2; ks++) {
      short8 af0 = *reinterpret_cast<const short8*>(&Al[r][ks * 32 + g * 8]);
      short8 af1 = *reinterpret_cast<const short8*>(&Al[16 + r][ks * 32 + g * 8]);
#pragma unroll
      for (int nt = 0; nt < 4; nt++) {
        short8 bb = *reinterpret_cast<const short8*>(&Bl[w * 64 + nt * 16 + r][ks * 32 + g * 8]);
        acc[0][nt] = __builtin_amdgcn_mfma_f32_16x16x32_bf16(af0, bb, acc[0][nt], 0, 0, 0);
        acc[1][nt] = __builtin_amdgcn_mfma_f32_16x16x32_bf16(af1, bb, acc[1][nt], 0, 0, 0);
      }
    }
  }
#pragma unroll
  for (int rt = 0; rt < 2; rt++)
#pragma unroll
    for (int nt = 0; nt < 4; nt++)
#pragma unroll
      for (int j = 0; j < 4; j++)
        Cl[rt * 16 + g * 4 + j][w * 64 + nt * 16 + r] = acc[rt][nt][j];
  __syncthreads();
  int row = tid >> 3, sub = tid & 7;
  int m = m0 + row;
  float x[32];
  float sum = 0.f, sumsq = 0.f;
#pragma unroll
  for (int i = 0; i < 8; i++) {
    int col = sub * 32 + i * 4;
    float4 xv = *reinterpret_cast<const float4*>(X + m * SD + col);
    float4 bb = *reinterpret_cast<const float4*>(bfv + col);
    x[i * 4 + 0] = Cl[row][col + 0] + xv.x + bb.x;
    x[i * 4 + 1] = Cl[row][col + 1] + xv.y + bb.y;
    x[i * 4 + 2] = Cl[row][col + 2] + xv.z + bb.z;
    x[i * 4 + 3] = Cl[row][col + 3] + xv.w + bb.w;
  }
#pragma unroll
  for (int c = 0; c < 32; c++) { sum += x[c]; sumsq += x[c] * x[c]; }
  sum += __shfl_xor(sum, 1);  sumsq += __shfl_xor(sumsq, 1);
  sum += __shfl_xor(sum, 2);  sumsq += __shfl_xor(sumsq, 2);
  sum += __shfl_xor(sum, 4);  sumsq += __shfl_xor(sumsq, 4);
  float mean = sum * (1.0f / 256.0f);
  float var = sumsq * (1.0f / 256.0f) - mean * mean;
  float rstd = rsqrtf(var + 1e-6f);
#pragma unroll
  for (int i = 0; i < 8; i++) {
    int col = sub * 32 + i * 4;
    float4 gv = *reinterpret_cast<const float4*>(gamma + col);
    float4 bv2 = *reinterpret_cast<const float4*>(beta + col);
    float4 ov;
    ov.x = (x[i * 4 + 0] - mean) * rstd * gv.x + bv2.x;
    ov.y = (x[i * 4 + 1] - mean) * rstd * gv.y + bv2.y;
    ov.z = (x[i * 4 + 2] - mean) * rstd * gv.z + bv2.z;
    ov.w = (x[i * 4 + 3] - mean) * rstd * gv.w + bv2.w;
    *reinterpret_cast<float4*>(out + m * SD + col) = ov;
  }
}

extern "C" void kernel_launch(void* const* d_in, const int* in_sizes, int n_in,
                              void* d_out, int out_size, void* d_ws, size_t ws_size,
                              hipStream_t stream) {
  const float* X  = (const float*)d_in[0];
  const float* Wq = (const float*)d_in[1];
  const float* Wk = (const float*)d_in[2];
  const float* Wv = (const float*)d_in[3];
  const float* Wf = (const float*)d_in[4];
  const float* bf = (const float*)d_in[5];
  const float* gm = (const float*)d_in[6];
  const float* bt = (const float*)d_in[7];
  float* out = (float*)d_out;
  unsigned short* ws = (unsigned short*)d_ws;

  convert_k<<<2304, 256, 0, stream>>>(X, Wq, Wk, Wv, Wf, ws);
  qkv_k<<<dim3(64, 6), 256, 0, stream>>>(ws, ws);
  attn_k<<<dim3(512), 512, 0, stream>>>(ws, ws);
  final_k<<<256, 256, 0, stream>>>(ws, X, bf, gm, bt, out);
}

// Round 7
// 58.801 us; speedup vs baseline: 1.4401x; 1.4401x over previous
//
#include <hip/hip_runtime.h>
#include <hip/hip_bf16.h>

typedef __attribute__((ext_vector_type(8))) short short8;
typedef __attribute__((ext_vector_type(4))) float f32x4;
typedef __attribute__((ext_vector_type(16))) float f32x16;

#define DEVI __device__ __forceinline__

DEVI unsigned short f2bf(float f) {
  union { float f; unsigned int u; } v; v.f = f;
  unsigned int r = v.u + 0x7fffu + ((v.u >> 16) & 1u);
  return (unsigned short)(r >> 16);
}

DEVI unsigned int cvt2(float lo, float hi) {  // v_cvt_pk_bf16_f32 (RNE)
  unsigned int r;
  asm("v_cvt_pk_bf16_f32 %0, %1, %2" : "=v"(r) : "v"(lo), "v"(hi));
  return r;
}

// direct global->LDS, 16B per lane. dest = wave-uniform base + lane*16 (linear).
#define GLDS16(gp, lp)                                                         \
  __builtin_amdgcn_global_load_lds(                                            \
      (const __attribute__((address_space(1))) unsigned int*)(uintptr_t)(gp),  \
      (__attribute__((address_space(3))) unsigned int*)(uintptr_t)(lp), 16, 0, 0)

// problem sizes
#define SB 4
#define SS 2048
#define SD 256
#define SH 8
#define SDH 32
#define SM 8192  // B*S

// softmax scale folded into Q:  (1/sqrt(S)) * log2(e)
#define QSCALE 0.0318793654f

// workspace layout (ushort element offsets) -- all bf16 intermediates
#define Q_OFF   0                 // [BH][S][dh]   (Q pre-scaled by QSCALE)
#define K_OFF   (SM * SD)         // [BH][S][dh]
#define VT_OFF  (2 * SM * SD)     // [BH][dh][S]  (V transposed)
#define AO_OFF  (3 * SM * SD)     // [M][D] attention output

// ---------------- kernel 1: fused convert + QKV projection, 128x128 tile ----
// Reads fp32 X and W directly; converts to bf16 in-register while staging.
// z = n0>>8 selects Wq/Wk/Wv. Epilogue stages C through LDS for coalesced
// stores (Q/K row-major; V transposed).
__global__ __launch_bounds__(256) void qkv_k(
    const float* __restrict__ X, const float* __restrict__ Wq,
    const float* __restrict__ Wk, const float* __restrict__ Wv,
    unsigned short* __restrict__ ws) {
  __shared__ __align__(16) unsigned short Atile[128][72];
  __shared__ __align__(16) unsigned short Btile[128][72];
  int tid = threadIdx.x, w = tid >> 6, lane = tid & 63, g = lane >> 4, r = lane & 15;
  int m0 = blockIdx.x * 128, n0 = blockIdx.y * 128;
  int z = n0 >> 8, nbase = n0 & 255;
  const float* Wz = (z == 0) ? Wq : (z == 1) ? Wk : Wv;
  int wr = (w >> 1) * 64, wc = (w & 1) * 64;
  f32x4 acc[4][4] = {};
  int srow = tid >> 3, scol = (tid & 7) * 8;
  float4 a0[4], a1[4], b0[4], b1[4];
#pragma unroll
  for (int p = 0; p < 4; ++p) {
    const float* xa = X + (m0 + srow + p * 32) * SD + scol;
    const float* xb = Wz + (nbase + srow + p * 32) * SD + scol;
    a0[p] = *reinterpret_cast<const float4*>(xa);
    a1[p] = *reinterpret_cast<const float4*>(xa + 4);
    b0[p] = *reinterpret_cast<const float4*>(xb);
    b1[p] = *reinterpret_cast<const float4*>(xb + 4);
  }
  for (int k0 = 0; k0 < SD; k0 += 64) {
    __syncthreads();
#pragma unroll
    for (int p = 0; p < 4; ++p) {
      uint4 ua = { cvt2(a0[p].x, a0[p].y), cvt2(a0[p].z, a0[p].w),
                   cvt2(a1[p].x, a1[p].y), cvt2(a1[p].z, a1[p].w) };
      uint4 ub = { cvt2(b0[p].x, b0[p].y), cvt2(b0[p].z, b0[p].w),
                   cvt2(b1[p].x, b1[p].y), cvt2(b1[p].z, b1[p].w) };
      *reinterpret_cast<uint4*>(&Atile[srow + p * 32][scol]) = ua;
      *reinterpret_cast<uint4*>(&Btile[srow + p * 32][scol]) = ub;
    }
    __syncthreads();
    if (k0 + 64 < SD) {
#pragma unroll
      for (int p = 0; p < 4; ++p) {
        const float* xa = X + (m0 + srow + p * 32) * SD + k0 + 64 + scol;
        const float* xb = Wz + (nbase + srow + p * 32) * SD + k0 + 64 + scol;
        a0[p] = *reinterpret_cast<const float4*>(xa);
        a1[p] = *reinterpret_cast<const float4*>(xa + 4);
        b0[p] = *reinterpret_cast<const float4*>(xb);
        b1[p] = *reinterpret_cast<const float4*>(xb + 4);
      }
    }
#pragma unroll
    for (int ks = 0; ks < 2; ++ks) {
      short8 af[4], bf[4];
#pragma unroll
      for (int i = 0; i < 4; ++i)
        af[i] = *reinterpret_cast<const short8*>(&Atile[wr + i * 16 + r][ks * 32 + g * 8]);
#pragma unroll
      for (int j = 0; j < 4; ++j)
        bf[j] = *reinterpret_cast<const short8*>(&Btile[wc + j * 16 + r][ks * 32 + g * 8]);
#pragma unroll
      for (int i = 0; i < 4; ++i)
#pragma unroll
        for (int j = 0; j < 4; ++j)
          acc[i][j] = __builtin_amdgcn_mfma_f32_16x16x32_bf16(af[i], bf[j], acc[i][j], 0, 0, 0);
    }
  }
  int b_ = m0 >> 11, sbase = m0 & 2047;
  float qs = (z == 0) ? QSCALE : 1.0f;
  unsigned short* Vt = &Btile[0][0];  // reused as [64][136]
#pragma unroll
  for (int p = 0; p < 2; ++p) {       // n-half pass: cols p*64 .. p*64+63
    __syncthreads();
    if ((w & 1) == p) {
      if (z < 2) {
#pragma unroll
        for (int i = 0; i < 4; ++i)
#pragma unroll
          for (int j = 0; j < 4; ++j)
#pragma unroll
            for (int jj = 0; jj < 4; ++jj)
              Atile[wr + i * 16 + g * 4 + jj][j * 16 + r] = f2bf(acc[i][j][jj] * qs);
      } else {
#pragma unroll
        for (int i = 0; i < 4; ++i)
#pragma unroll
          for (int j = 0; j < 4; ++j) {
            unsigned short o4[4];
#pragma unroll
            for (int jj = 0; jj < 4; ++jj) o4[jj] = f2bf(acc[i][j][jj]);
            *reinterpret_cast<uint2*>(&Vt[(j * 16 + r) * 136 + wr + i * 16 + g * 4]) =
                *reinterpret_cast<const uint2*>(o4);
          }
      }
    }
    __syncthreads();
    if (z < 2) {
      unsigned short* out = ws + (z == 0 ? Q_OFF : K_OFF);
      int h0 = (nbase + p * 64) >> 5;
#pragma unroll
      for (int it = 0; it < 4; ++it) {
        int c = it * 256 + tid;                  // 1024 chunks of 16B
        int m = c >> 3, cr = c & 7, hl = cr >> 2, ch = cr & 3;
        short8 val = *reinterpret_cast<const short8*>(&Atile[m][hl * 32 + ch * 8]);
        int h = h0 + hl;
        *reinterpret_cast<short8*>(
            out + (((b_ << 3) + h) * SS + sbase + m) * SDH + ch * 8) = val;
      }
    } else {
      unsigned short* out = ws + VT_OFF;
      int nb = nbase + p * 64;
#pragma unroll
      for (int it = 0; it < 4; ++it) {
        int c = it * 256 + tid;                  // 1024 chunks of 16B
        int nl = c >> 4, ch = c & 15;
        short8 val = *reinterpret_cast<const short8*>(&Vt[nl * 136 + ch * 8]);
        int col = nb + nl, h = col >> 5, d = col & 31;
        *reinterpret_cast<short8*>(
            out + ((((b_ << 3) + h) << 5) + d) * SS + sbase + ch * 8) = val;
      }
    }
  }
}

// ---------------- kernel 2: flash attention ----------------
// 512 blocks (32 bh x 16 qb, XCD-swizzled) x 512 thr = 8 waves.
// Waves 0-3: kv [0,1024), waves 4-7: kv [1024,2048); each wave 32 q rows.
// TKV=128 per barrier pair, double-buffered global_load_lds (counted vmcnt(4)).
// Bank-exact swizzles: K (64B rows): chunk s = l ^ ((row>>1)&3) -> every
// 16-lane phase covers 8 distinct 4-bank positions x2 (free). V (128B rows):
// s = l ^ (row&7). L computed by MFMA with ones-B (lands in O's layout).
__global__ __launch_bounds__(512, 4) void attn_k(const unsigned short* __restrict__ ws_c,
                                                 unsigned short* __restrict__ ws) {
  __shared__ __align__(16) unsigned char smem[65536];
  int tid = threadIdx.x, w = tid >> 6, lane = tid & 63;
  int wg = w >> 2, wl = w & 3, gtid = tid & 255;
  int n32 = lane & 31, hi = lane >> 5;
  // XCD-aware swizzle (512 % 8 == 0 -> bijective)
  int wgid = ((blockIdx.x & 7) << 6) + (blockIdx.x >> 3);
  int bh = wgid >> 4, qb = wgid & 15;
  int q0 = qb * 128 + wl * 32;
  const unsigned short* Qh = ws_c + Q_OFF + bh * (SS * SDH);
  const unsigned short* Kg = ws_c + K_OFF + (bh * SS + wg * 1024) * SDH;
  const unsigned short* Vg = ws_c + VT_OFF + bh * (SDH * SS) + wg * 1024;
  // Q B-frags: lane holds col q=n32, k = 8*hi + j (dh halves)
  short8 qB0 = *reinterpret_cast<const short8*>(Qh + (q0 + n32) * SDH + 8 * hi);
  short8 qB1 = *reinterpret_cast<const short8*>(Qh + (q0 + n32) * SDH + 16 + 8 * hi);
  // LDS regions: K[grp][buf] 8KB each; V[grp][buf] 8KB each
  unsigned short* Kbuf0 = (unsigned short*)(smem + wg * 16384);
  unsigned short* Kbuf1 = (unsigned short*)(smem + wg * 16384 + 8192);
  unsigned short* Vbuf0 = (unsigned short*)(smem + 32768 + wg * 16384);
  unsigned short* Vbuf1 = (unsigned short*)(smem + 32768 + wg * 16384 + 8192);
  int wv = gtid >> 6;  // wave index within 256-thread group (wave-uniform)
  // staging sources (inverse-swizzled so linear LDS dest ends up swizzled)
  int kr = gtid >> 2;
  int kcg = (gtid & 3) ^ ((kr >> 1) & 3);
  const unsigned short* gK0 = Kg + kr * SDH + kcg * 8;   // rows 0-63 of tile
  const unsigned short* gK1 = gK0 + 64 * SDH;            // rows 64-127
  int vr = gtid >> 4;
  int vcg = (gtid & 15) ^ (vr & 7);
  const unsigned short* gV0 = Vg + vr * SS + vcg * 8;    // d rows 0-15
  const unsigned short* gV1 = gV0 + 16 * SS;             // d rows 16-31
  auto issue = [&](int buf, int tt) {
    char* kd = (char*)(buf ? Kbuf1 : Kbuf0) + wv * 1024;
    char* vd = (char*)(buf ? Vbuf1 : Vbuf0) + wv * 1024;
    GLDS16(gK0 + tt * 4096, kd);
    GLDS16(gK1 + tt * 4096, kd + 4096);
    GLDS16(gV0 + tt * 128, vd);
    GLDS16(gV1 + tt * 128, vd + 4096);
  };
  issue(0, 0);
  f32x16 O = {}, Lf = {};
  union { unsigned int u[4]; short8 sv; } ONES;
  ONES.u[0] = 0x3F803F80u; ONES.u[1] = 0x3F803F80u;
  ONES.u[2] = 0x3F803F80u; ONES.u[3] = 0x3F803F80u;
  // read-side swizzle constants
  int rb = (n32 >> 1) & 3;
  int koff0 = (hi ^ rb) * 8;          // K logical chunk l=hi
  int koff1 = ((2 + hi) ^ rb) * 8;    // K logical chunk l=2+hi
  int vb7 = n32 & 7;
  for (int t = 0; t < 8; ++t) {
    const unsigned short* Kt = (t & 1) ? Kbuf1 : Kbuf0;
    const unsigned short* Vt = (t & 1) ? Vbuf1 : Vbuf0;
    if (t < 7) {
      issue((t + 1) & 1, t + 1);
      asm volatile("s_waitcnt vmcnt(4)" ::: "memory");  // tile t landed; t+1 in flight
    } else {
      asm volatile("s_waitcnt vmcnt(0)" ::: "memory");
    }
    __builtin_amdgcn_s_barrier();
#pragma unroll
    for (int batch = 0; batch < 2; ++batch) {
      int sub0 = batch * 2, sub1 = batch * 2 + 1;
      const unsigned short* kr0 = Kt + (sub0 * 32 + n32) * 32;
      const unsigned short* kr1 = Kt + (sub1 * 32 + n32) * 32;
      short8 kA00 = *reinterpret_cast<const short8*>(kr0 + koff0);
      short8 kA01 = *reinterpret_cast<const short8*>(kr0 + koff1);
      short8 kA10 = *reinterpret_cast<const short8*>(kr1 + koff0);
      short8 kA11 = *reinterpret_cast<const short8*>(kr1 + koff1);
      f32x16 a0 = {}, a1 = {};
      __builtin_amdgcn_s_setprio(1);
      a0 = __builtin_amdgcn_mfma_f32_32x32x16_bf16(kA00, qB0, a0, 0, 0, 0);
      a1 = __builtin_amdgcn_mfma_f32_32x32x16_bf16(kA10, qB0, a1, 0, 0, 0);
      a0 = __builtin_amdgcn_mfma_f32_32x32x16_bf16(kA01, qB1, a0, 0, 0, 0);
      a1 = __builtin_amdgcn_mfma_f32_32x32x16_bf16(kA11, qB1, a1, 0, 0, 0);
      __builtin_amdgcn_s_setprio(0);
#pragma unroll
      for (int i = 0; i < 16; ++i) a0[i] = __builtin_amdgcn_exp2f(a0[i]);
#pragma unroll
      for (int i = 0; i < 16; ++i) a1[i] = __builtin_amdgcn_exp2f(a1[i]);
      // P -> PV A-frags via cvt_pk + permlane32_swap (derived+verified R1)
      unsigned int pk0[8], pk1[8];
#pragma unroll
      for (int i = 0; i < 8; ++i) {
        pk0[i] = cvt2(a0[2 * i], a0[2 * i + 1]);
        pk1[i] = cvt2(a1[2 * i], a1[2 * i + 1]);
      }
      asm("v_permlane32_swap_b32 %0, %1" : "+v"(pk0[0]), "+v"(pk0[2]));
      asm("v_permlane32_swap_b32 %0, %1" : "+v"(pk0[1]), "+v"(pk0[3]));
      asm("v_permlane32_swap_b32 %0, %1" : "+v"(pk0[4]), "+v"(pk0[6]));
      asm("v_permlane32_swap_b32 %0, %1" : "+v"(pk0[5]), "+v"(pk0[7]));
      asm("v_permlane32_swap_b32 %0, %1" : "+v"(pk1[0]), "+v"(pk1[2]));
      asm("v_permlane32_swap_b32 %0, %1" : "+v"(pk1[1]), "+v"(pk1[3]));
      asm("v_permlane32_swap_b32 %0, %1" : "+v"(pk1[4]), "+v"(pk1[6]));
      asm("v_permlane32_swap_b32 %0, %1" : "+v"(pk1[5]), "+v"(pk1[7]));
      union { unsigned int u[4]; short8 sv; } A10, A20, A11, A21;
      A10.u[0] = pk0[0]; A10.u[1] = pk0[1]; A10.u[2] = pk0[2]; A10.u[3] = pk0[3];
      A20.u[0] = pk0[4]; A20.u[1] = pk0[5]; A20.u[2] = pk0[6]; A20.u[3] = pk0[7];
      A11.u[0] = pk1[0]; A11.u[1] = pk1[1]; A11.u[2] = pk1[2]; A11.u[3] = pk1[3];
      A21.u[0] = pk1[4]; A21.u[1] = pk1[5]; A21.u[2] = pk1[6]; A21.u[3] = pk1[7];
      const unsigned short* vrow = Vt + n32 * 128;
      short8 vB00 = *reinterpret_cast<const short8*>(vrow + ((sub0 * 4 + hi) ^ vb7) * 8);
      short8 vB01 = *reinterpret_cast<const short8*>(vrow + ((sub0 * 4 + 2 + hi) ^ vb7) * 8);
      short8 vB10 = *reinterpret_cast<const short8*>(vrow + ((sub1 * 4 + hi) ^ vb7) * 8);
      short8 vB11 = *reinterpret_cast<const short8*>(vrow + ((sub1 * 4 + 2 + hi) ^ vb7) * 8);
      __builtin_amdgcn_s_setprio(1);
      O = __builtin_amdgcn_mfma_f32_32x32x16_bf16(A10.sv, vB00, O, 0, 0, 0);
      O = __builtin_amdgcn_mfma_f32_32x32x16_bf16(A20.sv, vB01, O, 0, 0, 0);
      O = __builtin_amdgcn_mfma_f32_32x32x16_bf16(A11.sv, vB10, O, 0, 0, 0);
      O = __builtin_amdgcn_mfma_f32_32x32x16_bf16(A21.sv, vB11, O, 0, 0, 0);
      Lf = __builtin_amdgcn_mfma_f32_32x32x16_bf16(A10.sv, ONES.sv, Lf, 0, 0, 0);
      Lf = __builtin_amdgcn_mfma_f32_32x32x16_bf16(A20.sv, ONES.sv, Lf, 0, 0, 0);
      Lf = __builtin_amdgcn_mfma_f32_32x32x16_bf16(A11.sv, ONES.sv, Lf, 0, 0, 0);
      Lf = __builtin_amdgcn_mfma_f32_32x32x16_bf16(A21.sv, ONES.sv, Lf, 0, 0, 0);
      __builtin_amdgcn_s_setprio(0);
    }
    __builtin_amdgcn_s_barrier();
  }
  // combine the two kv-groups (fixed-M softmax -> O,L add linearly).
  // Conflict-free layout: OC[i][p] row-major, p = wl*64+lane consecutive.
  __syncthreads();
  float* OCf = reinterpret_cast<float*>(smem);           // [16][257]
  float* LCf = OCf + 16 * 257;                           // [16][257]
  int p = wl * 64 + lane;
  if (wg == 1) {
#pragma unroll
    for (int i = 0; i < 16; ++i) { OCf[i * 257 + p] = O[i]; LCf[i * 257 + p] = Lf[i]; }
  }
  __syncthreads();
  if (wg == 0) {
    int b = bh >> 3, h = bh & 7;
    unsigned short* AO = ws + AO_OFF;
#pragma unroll
    for (int rr = 0; rr < 16; ++rr) {
      float Ot = O[rr] + OCf[rr * 257 + p];
      float Lt = Lf[rr] + LCf[rr * 257 + p];
      int q = (rr & 3) + 8 * (rr >> 2) + 4 * hi;
      AO[(b * SS + q0 + q) * SD + h * SDH + n32] = f2bf(Ot / Lt);
    }
  }
}

// ---------------- kernel 3: out-proj + bias + residual + LayerNorm ----------
// Wf read as fp32, converted during LDS staging.
__global__ __launch_bounds__(256) void final_k(
    const unsigned short* __restrict__ ws_c, const float* __restrict__ X,
    const float* __restrict__ Wf, const float* __restrict__ bfv,
    const float* __restrict__ gamma, const float* __restrict__ beta,
    float* __restrict__ out) {
  __shared__ __align__(16) unsigned short Al[32][72];
  __shared__ __align__(16) unsigned short Bl[256][72];
  __shared__ float Cl[32][257];
  const unsigned short* AO = ws_c + AO_OFF;
  int tid = threadIdx.x, w = tid >> 6, lane = tid & 63, g = lane >> 4, r = lane & 15;
  int m0 = blockIdx.x * 32;
  f32x4 acc[2][4] = {};
  int arow = tid >> 3, acol = (tid & 7) * 8;
  for (int k0 = 0; k0 < SD; k0 += 64) {
    short8 av = *reinterpret_cast<const short8*>(AO + (m0 + arow) * SD + k0 + acol);
    float4 w0[8], w1[8];
#pragma unroll
    for (int i = 0; i < 8; i++) {
      const float* wp = Wf + (i * 32 + arow) * SD + k0 + acol;
      w0[i] = *reinterpret_cast<const float4*>(wp);
      w1[i] = *reinterpret_cast<const float4*>(wp + 4);
    }
    __syncthreads();
    *reinterpret_cast<short8*>(&Al[arow][acol]) = av;
#pragma unroll
    for (int i = 0; i < 8; i++) {
      uint4 ub = { cvt2(w0[i].x, w0[i].y), cvt2(w0[i].z, w0[i].w),
                   cvt2(w1[i].x, w1[i].y), cvt2(w1[i].z, w1[i].w) };
      *reinterpret_cast<uint4*>(&Bl[i * 32 + arow][acol]) = ub;
    }
    __syncthreads();
#pragma unroll
    for (int ks = 0; ks < 2; ks++) {
      short8 af0 = *reinterpret_cast<const short8*>(&Al[r][ks * 32 + g * 8]);
      short8 af1 = *reinterpret_cast<const short8*>(&Al[16 + r][ks * 32 + g * 8]);
#pragma unroll
      for (int nt = 0; nt < 4; nt++) {
        short8 bb = *reinterpret_cast<const short8*>(&Bl[w * 64 + nt * 16 + r][ks * 32 + g * 8]);
        acc[0][nt] = __builtin_amdgcn_mfma_f32_16x16x32_bf16(af0, bb, acc[0][nt], 0, 0, 0);
        acc[1][nt] = __builtin_amdgcn_mfma_f32_16x16x32_bf16(af1, bb, acc[1][nt], 0, 0, 0);
      }
    }
  }
#pragma unroll
  for (int rt = 0; rt < 2; rt++)
#pragma unroll
    for (int nt = 0; nt < 4; nt++)
#pragma unroll
      for (int j = 0; j < 4; j++)
        Cl[rt * 16 + g * 4 + j][w * 64 + nt * 16 + r] = acc[rt][nt][j];
  __syncthreads();
  int row = tid >> 3, sub = tid & 7;
  int m = m0 + row;
  float x[32];
  float sum = 0.f, sumsq = 0.f;
#pragma unroll
  for (int i = 0; i < 8; i++) {
    int col = sub * 32 + i * 4;
    float4 xv = *reinterpret_cast<const float4*>(X + m * SD + col);
    float4 bb = *reinterpret_cast<const float4*>(bfv + col);
    x[i * 4 + 0] = Cl[row][col + 0] + xv.x + bb.x;
    x[i * 4 + 1] = Cl[row][col + 1] + xv.y + bb.y;
    x[i * 4 + 2] = Cl[row][col + 2] + xv.z + bb.z;
    x[i * 4 + 3] = Cl[row][col + 3] + xv.w + bb.w;
  }
#pragma unroll
  for (int c = 0; c < 32; c++) { sum += x[c]; sumsq += x[c] * x[c]; }
  sum += __shfl_xor(sum, 1);  sumsq += __shfl_xor(sumsq, 1);
  sum += __shfl_xor(sum, 2);  sumsq += __shfl_xor(sumsq, 2);
  sum += __shfl_xor(sum, 4);  sumsq += __shfl_xor(sumsq, 4);
  float mean = sum * (1.0f / 256.0f);
  float var = sumsq * (1.0f / 256.0f) - mean * mean;
  float rstd = rsqrtf(var + 1e-6f);
#pragma unroll
  for (int i = 0; i < 8; i++) {
    int col = sub * 32 + i * 4;
    float4 gv = *reinterpret_cast<const float4*>(gamma + col);
    float4 bv2 = *reinterpret_cast<const float4*>(beta + col);
    float4 ov;
    ov.x = (x[i * 4 + 0] - mean) * rstd * gv.x + bv2.x;
    ov.y = (x[i * 4 + 1] - mean) * rstd * gv.y + bv2.y;
    ov.z = (x[i * 4 + 2] - mean) * rstd * gv.z + bv2.z;
    ov.w = (x[i * 4 + 3] - mean) * rstd * gv.w + bv2.w;
    *reinterpret_cast<float4*>(out + m * SD + col) = ov;
  }
}

extern "C" void kernel_launch(void* const* d_in, const int* in_sizes, int n_in,
                              void* d_out, int out_size, void* d_ws, size_t ws_size,
                              hipStream_t stream) {
  const float* X  = (const float*)d_in[0];
  const float* Wq = (const float*)d_in[1];
  const float* Wk = (const float*)d_in[2];
  const float* Wv = (const float*)d_in[3];
  const float* Wf = (const float*)d_in[4];
  const float* bf = (const float*)d_in[5];
  const float* gm = (const float*)d_in[6];
  const float* bt = (const float*)d_in[7];
  float* out = (float*)d_out;
  unsigned short* ws = (unsigned short*)d_ws;

  qkv_k<<<dim3(64, 6), 256, 0, stream>>>(X, Wq, Wk, Wv, ws);
  attn_k<<<dim3(512), 512, 0, stream>>>(ws, ws);
  final_k<<<256, 256, 0, stream>>>(ws, X, Wf, bf, gm, bt, out);
}